// Round 9
// baseline (164.713 us; speedup 1.0000x reference)
//
#include <hip/hip_runtime.h>
#include <hip/hip_bf16.h>
#include <cstdint>
#include <cstddef>

#define NB    1024          // batch (graphs)
#define NF    32            // fields per graph
#define DIN   64
#define HID   128
#define HEADS 4
#define NTOT  (NB*NF)       // 32768 nodes
#define H1DIM (HEADS*HID)   // 512

typedef __attribute__((ext_vector_type(8))) short          bf16x8;
typedef __attribute__((ext_vector_type(8))) unsigned short u16x8;
typedef __attribute__((ext_vector_type(4))) float          f32x4;

__device__ __forceinline__ float bf2f(unsigned short u) {
    return __uint_as_float(((unsigned)u) << 16);
}
__device__ __forceinline__ unsigned short f2bf(float f) {
    unsigned u = __float_as_uint(f);
    return (unsigned short)((u + 0x7FFF + ((u >> 16) & 1)) >> 16);   // RNE
}

// ---- swizzled LDS index helpers (u16-element index; 16B-chunk XOR) --------
__device__ __forceinline__ int x0_at(int r, int c) {        // [32][128]
    return r * 128 + ((((c >> 3) ^ (r & 7)) & 15) << 3) + (c & 7);
}
__device__ __forceinline__ int hT_at(int f, int s) {        // [128][32]
    return f * 32 + ((((s >> 3) ^ ((f >> 1) & 3)) & 3) << 3) + (s & 7);
}
__device__ __forceinline__ int al_at(int d, int s) {        // [32][32]
    return d * 32 + ((((s >> 3) ^ ((d >> 1) & 3)) & 3) << 3) + (s & 7);
}
__device__ __forceinline__ int x1_at(int r, int c) {        // [32][512]
    return r * 512 + ((((c >> 3) ^ ((r >> 1) & 7)) & 63) << 3) + (c & 7);
}

// ---------------------------------------------------------------------------
// weight prep: w1T[512][128], w2T[128][512], WaT[128][64]  (all bf16, B^T)
// ---------------------------------------------------------------------------
__global__ __launch_bounds__(256) void k_prep(
    const float* __restrict__ w1, const float* __restrict__ w2,
    const float* __restrict__ Wa,
    unsigned short* __restrict__ w1T, unsigned short* __restrict__ w2T,
    unsigned short* __restrict__ WaT)
{
    int i = blockIdx.x * 256 + threadIdx.x;
    if (i < HID * H1DIM) {                   // w1T[n][k] = w1[k][n]
        int n = i >> 7, k = i & 127;
        w1T[i] = f2bf(w1[k * H1DIM + n]);
    } else if (i < 2 * HID * H1DIM) {        // w2T[n][k] = w2[k][n]
        int j = i - HID * H1DIM;
        int n = j >> 9, k = j & 511;
        w2T[j] = f2bf(w2[k * HID + n]);
    } else {                                 // WaT[c][k] = Wa[k][c]
        int j = i - 2 * HID * H1DIM;
        int c = j >> 6, k = j & 63;
        WaT[j] = f2bf(Wa[k * HID + c]);
    }
}

// ---------------------------------------------------------------------------
// Kernel A: one block = (graph b, head h). 128 thr = 2 waves.
// cnt | aligner+LN+gate | GEMM1(head) +logits | softmax | PV1 | ELU -> x1g
// LDS 14592 B -> 11 blocks/CU.
//   [0,8192)     : x0L u16[32][128] swz -> h1T u16[128][32] swz
//   [0,8704)     : x1Ls u16[32][136]  (after h1T dead)
//   [8192,12288) : cntI int[1024]  (dead after convert)
//   [10240,12288): alphaL u16[32][32] swz (written post-bar4)
//   [12288,13312): cntB u8[1024]
//   [13312,...)  : lnSp,lnS2p,esP,edP f32[2][32] each; rsumL f32[32]
// ---------------------------------------------------------------------------
__global__ __launch_bounds__(128) void k_gnn1(
    const float* __restrict__ xf, const unsigned short* __restrict__ WaT,
    const float* __restrict__ ba, const float* __restrict__ gamma,
    const float* __restrict__ beta, const float* __restrict__ gl,
    const unsigned short* __restrict__ w1T, const float* __restrict__ as1,
    const float* __restrict__ ad1, const float* __restrict__ b1,
    const int* __restrict__ src, const int* __restrict__ dst, int epg,
    unsigned short* __restrict__ x1g)
{
    __shared__ __align__(16) char S[14592];
    unsigned short* x0L    = (unsigned short*)S;
    unsigned short* h1T    = (unsigned short*)S;
    unsigned short* x1Ls   = (unsigned short*)S;
    int*            cntI   = (int*)(S + 8192);
    unsigned short* alphaL = (unsigned short*)(S + 10240);
    unsigned char*  cntB   = (unsigned char*)(S + 12288);
    float* lnSp  = (float*)(S + 13312);
    float* lnS2p = (float*)(S + 13568);
    float* esP   = (float*)(S + 13824);
    float* edP   = (float*)(S + 14080);
    float* rsumL = (float*)(S + 14336);

    const int bid = blockIdx.x;
    const int b = bid >> 2, h = bid & 3;
    const int t = threadIdx.x;
    const int w2 = t >> 6, l = t & 63;
    const int g = l >> 4, i16 = l & 15;
    const int nb = b * NF;
    const f32x4 zf4 = {0.f, 0.f, 0.f, 0.f};

    // ---------------- P0: edge count matrix --------------------------------
    for (int i = t; i < NF * NF; i += 128) cntI[i] = 0;
    __syncthreads();
    for (int i = t; i < epg; i += 128) {
        int sv = src[b * epg + i] - nb;
        int dv = dst[b * epg + i] - nb;
        atomicAdd(&cntI[dv * NF + sv], 1);
    }
    if (t < NF) atomicAdd(&cntI[t * 33], 1);   // self-loops
    __syncthreads();
    for (int i = t; i < NF * NF; i += 128) {
        int c = cntI[i];
        cntB[i] = (unsigned char)(c > 255 ? 255 : c);
    }

    // ---------------- P1: aligner GEMM (32x128, K=64) + LN + gate ----------
    f32x4 accA[2][4];
    #pragma unroll
    for (int m = 0; m < 2; ++m)
        #pragma unroll
        for (int n = 0; n < 4; ++n) accA[m][n] = zf4;

    #pragma unroll
    for (int k = 0; k < 2; ++k) {
        bf16x8 aF[2];
        #pragma unroll
        for (int m = 0; m < 2; ++m) {
            const float* p = &xf[(size_t)(nb + m * 16 + i16) * DIN + k * 32 + g * 8];
            float4 f0 = *(const float4*)p;
            float4 f1 = *(const float4*)(p + 4);
            u16x8 v;
            v[0] = f2bf(f0.x); v[1] = f2bf(f0.y); v[2] = f2bf(f0.z); v[3] = f2bf(f0.w);
            v[4] = f2bf(f1.x); v[5] = f2bf(f1.y); v[6] = f2bf(f1.z); v[7] = f2bf(f1.w);
            aF[m] = (bf16x8)v;
        }
        #pragma unroll
        for (int n = 0; n < 4; ++n) {
            bf16x8 bF = *(const bf16x8*)&WaT[(size_t)(w2 * 64 + n * 16 + i16) * DIN + k * 32 + g * 8];
            #pragma unroll
            for (int m = 0; m < 2; ++m)
                accA[m][n] = __builtin_amdgcn_mfma_f32_16x16x32_bf16(aF[m], bF, accA[m][n], 0, 0, 0);
        }
    }
    float val[2][4][4];
    float ps[2][4], ps2[2][4];
    #pragma unroll
    for (int m = 0; m < 2; ++m)
        #pragma unroll
        for (int v = 0; v < 4; ++v) { ps[m][v] = 0.f; ps2[m][v] = 0.f; }
    #pragma unroll
    for (int n = 0; n < 4; ++n) {
        float bav = ba[w2 * 64 + n * 16 + i16];
        #pragma unroll
        for (int m = 0; m < 2; ++m)
            #pragma unroll
            for (int v = 0; v < 4; ++v) {
                float a = accA[m][n][v] + bav;
                val[m][n][v] = a;
                ps[m][v] += a; ps2[m][v] += a * a;
            }
    }
    #pragma unroll
    for (int o = 1; o < 16; o <<= 1) {
        #pragma unroll
        for (int m = 0; m < 2; ++m)
            #pragma unroll
            for (int v = 0; v < 4; ++v) {
                ps[m][v]  += __shfl_xor(ps[m][v], o);
                ps2[m][v] += __shfl_xor(ps2[m][v], o);
            }
    }
    if (i16 == 0) {
        #pragma unroll
        for (int m = 0; m < 2; ++m)
            #pragma unroll
            for (int v = 0; v < 4; ++v) {
                int r = m * 16 + g * 4 + v;
                lnSp[w2 * 32 + r]  = ps[m][v];
                lnS2p[w2 * 32 + r] = ps2[m][v];
            }
    }
    __syncthreads();
    #pragma unroll
    for (int m = 0; m < 2; ++m)
        #pragma unroll
        for (int v = 0; v < 4; ++v) {
            int r = m * 16 + g * 4 + v;
            float S1 = lnSp[r] + lnSp[32 + r];
            float S2 = lnS2p[r] + lnS2p[32 + r];
            float mu = S1 * (1.0f / HID);
            float var = S2 * (1.0f / HID) - mu * mu;
            float rs = rsqrtf(var + 1e-5f);
            float gt = 1.0f / (1.0f + __expf(-gl[r]));
            #pragma unroll
            for (int n = 0; n < 4; ++n) {
                int c = w2 * 64 + n * 16 + i16;
                float xv = ((val[m][n][v] - mu) * rs * gamma[c] + beta[c]) * gt;
                x0L[x0_at(r, c)] = f2bf(xv);
            }
        }
    __syncthreads();

    // ---------------- P2: GEMM1 head slice (32x128, K=128) -----------------
    f32x4 acc1[2][4];
    #pragma unroll
    for (int m = 0; m < 2; ++m)
        #pragma unroll
        for (int n = 0; n < 4; ++n) acc1[m][n] = zf4;

    #pragma unroll
    for (int k = 0; k < 4; ++k) {
        bf16x8 aF[2];
        #pragma unroll
        for (int m = 0; m < 2; ++m)
            aF[m] = *(const bf16x8*)&x0L[x0_at(m * 16 + i16, k * 32 + g * 8)];
        #pragma unroll
        for (int n = 0; n < 4; ++n) {
            bf16x8 bF = *(const bf16x8*)&w1T[(size_t)(h * 128 + w2 * 64 + n * 16 + i16) * 128 + k * 32 + g * 8];
            #pragma unroll
            for (int m = 0; m < 2; ++m)
                acc1[m][n] = __builtin_amdgcn_mfma_f32_16x16x32_bf16(aF[m], bF, acc1[m][n], 0, 0, 0);
        }
    }
    __syncthreads();                 // x0L reads done; region becomes h1T

    // logits partials + transposed h1 store
    {
        float asv[4], adv[4];
        #pragma unroll
        for (int n = 0; n < 4; ++n) {
            int f = h * 128 + w2 * 64 + n * 16 + i16;
            asv[n] = as1[f]; adv[n] = ad1[f];
        }
        float pe[2][4], pd[2][4];
        #pragma unroll
        for (int m = 0; m < 2; ++m)
            #pragma unroll
            for (int v = 0; v < 4; ++v) {
                float e = 0.f, d = 0.f;
                #pragma unroll
                for (int n = 0; n < 4; ++n) {
                    e = fmaf(acc1[m][n][v], asv[n], e);
                    d = fmaf(acc1[m][n][v], adv[n], d);
                }
                pe[m][v] = e; pd[m][v] = d;
            }
        #pragma unroll
        for (int o = 1; o < 16; o <<= 1) {
            #pragma unroll
            for (int m = 0; m < 2; ++m)
                #pragma unroll
                for (int v = 0; v < 4; ++v) {
                    pe[m][v] += __shfl_xor(pe[m][v], o);
                    pd[m][v] += __shfl_xor(pd[m][v], o);
                }
        }
        if (i16 == 0) {
            #pragma unroll
            for (int m = 0; m < 2; ++m)
                #pragma unroll
                for (int v = 0; v < 4; ++v) {
                    int r = m * 16 + g * 4 + v;
                    esP[w2 * 32 + r] = pe[m][v];
                    edP[w2 * 32 + r] = pd[m][v];
                }
        }
        #pragma unroll
        for (int m = 0; m < 2; ++m)
            #pragma unroll
            for (int n = 0; n < 4; ++n) {
                int f = w2 * 64 + n * 16 + i16;      // head-local feature
                int s0 = m * 16 + g * 4;
                unsigned d0 = (unsigned)f2bf(acc1[m][n][0]) | ((unsigned)f2bf(acc1[m][n][1]) << 16);
                unsigned d1 = (unsigned)f2bf(acc1[m][n][2]) | ((unsigned)f2bf(acc1[m][n][3]) << 16);
                uint2 pk = {d0, d1};
                *(uint2*)&h1T[hT_at(f, s0)] = pk;
            }
    }
    __syncthreads();

    // ---------------- P3: softmax (4 lanes per dest row, 8-iter) -----------
    {
        int d = t >> 2, q = t & 3;
        float edv = edP[d] + edP[32 + d];
        float mx = -INFINITY;
        #pragma unroll
        for (int j = 0; j < 8; ++j) {
            int s = q * 8 + j;
            if (cntB[d * NF + s]) {
                float lg = esP[s] + esP[32 + s] + edv;
                lg = fmaxf(lg, 0.2f * lg);
                mx = fmaxf(mx, lg);
            }
        }
        mx = fmaxf(mx, __shfl_xor(mx, 1));
        mx = fmaxf(mx, __shfl_xor(mx, 2));
        float sum = 0.f;
        u16x8 av;
        #pragma unroll
        for (int j = 0; j < 8; ++j) {
            int s = q * 8 + j;
            int c = cntB[d * NF + s];
            float a = 0.f;
            if (c) {
                float lg = esP[s] + esP[32 + s] + edv;
                lg = fmaxf(lg, 0.2f * lg);
                a = (float)c * __expf(lg - mx);
                sum += a;
            }
            av[j] = f2bf(a);
        }
        *(u16x8*)&alphaL[al_at(d, q * 8)] = av;
        sum += __shfl_xor(sum, 1);
        sum += __shfl_xor(sum, 2);
        if (q == 0) rsumL[d] = 1.0f / sum;
    }
    __syncthreads();

    // ---------------- P4: PV1 = alpha(32x32) @ h1(32x128) ------------------
    f32x4 po[2][4];
    {
        bf16x8 aF2[2];
        #pragma unroll
        for (int m = 0; m < 2; ++m)
            aF2[m] = *(const bf16x8*)&alphaL[al_at(m * 16 + i16, g * 8)];
        #pragma unroll
        for (int n = 0; n < 4; ++n) {
            bf16x8 bF = *(const bf16x8*)&h1T[hT_at(w2 * 64 + n * 16 + i16, g * 8)];
            #pragma unroll
            for (int m = 0; m < 2; ++m)
                po[m][n] = __builtin_amdgcn_mfma_f32_16x16x32_bf16(aF2[m], bF, zf4, 0, 0, 0);
        }
    }
    __syncthreads();                 // h1T reads done; region becomes x1Ls

    // ELU epilogue into x1Ls [32][136]
    #pragma unroll
    for (int m = 0; m < 2; ++m)
        #pragma unroll
        for (int n = 0; n < 4; ++n) {
            int c = w2 * 64 + n * 16 + i16;
            float bias = b1[h * 128 + c];
            #pragma unroll
            for (int v = 0; v < 4; ++v) {
                int r = m * 16 + g * 4 + v;
                float x = po[m][n][v] * rsumL[r] + bias;
                x = (x > 0.f) ? x : (__expf(x) - 1.0f);
                x1Ls[r * 136 + c] = f2bf(x);
            }
        }
    __syncthreads();

    // coalesced global write of the head slice
    #pragma unroll
    for (int j = 0; j < 4; ++j) {
        int cidx = j * 128 + t;
        int r = cidx >> 4, ch = cidx & 15;
        u16x8 vv = *(const u16x8*)&x1Ls[r * 136 + ch * 8];
        *(u16x8*)&x1g[(size_t)(nb + r) * H1DIM + h * 128 + ch * 8] = vv;
    }
}

// ---------------------------------------------------------------------------
// Kernel B: one block = one graph. 256 thr = 4 waves.
// stage x1 | GEMM2 + logits2 | softmax2 | column sums | pool -> dout
// LDS 39424 B -> 4 blocks/CU.
// ---------------------------------------------------------------------------
__global__ __launch_bounds__(256) void k_gnn2(
    const unsigned short* __restrict__ x1g, const unsigned short* __restrict__ w2T,
    const float* __restrict__ as2, const float* __restrict__ ad2,
    const float* __restrict__ b2, const float* __restrict__ gl,
    const int* __restrict__ src, const int* __restrict__ dst, int epg,
    float* __restrict__ dout)
{
    __shared__ __align__(16) char S[39424];
    unsigned short* x1L  = (unsigned short*)S;             // [0,32768) swz
    int*            cntI = (int*)(S + 32768);              // -> aL2 alias
    float*          aL2  = (float*)(S + 32768);            // [32][33]
    unsigned char*  cntB = (unsigned char*)(S + 37120);
    float* esP = (float*)(S + 38144);                      // [4][32]
    float* edP = (float*)(S + 38656);
    float* rs2 = (float*)(S + 39168);
    float* wn2 = (float*)(S + 39296);

    const int b = blockIdx.x, t = threadIdx.x;
    const int w = t >> 6, l = t & 63;
    const int g = l >> 4, i16 = l & 15;
    const int nb = b * NF;
    const f32x4 zf4 = {0.f, 0.f, 0.f, 0.f};

    // P0: cnt
    for (int i = t; i < NF * NF; i += 256) cntI[i] = 0;
    __syncthreads();
    for (int i = t; i < epg; i += 256) {
        int sv = src[b * epg + i] - nb;
        int dv = dst[b * epg + i] - nb;
        atomicAdd(&cntI[dv * NF + sv], 1);
    }
    if (t < NF) atomicAdd(&cntI[t * 33], 1);
    __syncthreads();
    for (int i = t; i < NF * NF; i += 256) {
        int c = cntI[i];
        cntB[i] = (unsigned char)(c > 255 ? 255 : c);
    }
    // P1: stage x1 -> LDS (swizzled)
    #pragma unroll
    for (int j = 0; j < 8; ++j) {
        int idx = j * 256 + t;
        int r = idx >> 6, ch = idx & 63;
        u16x8 vv = *(const u16x8*)&x1g[(size_t)(nb + r) * H1DIM + ch * 8];
        *(u16x8*)&x1L[x1_at(r, ch * 8)] = vv;
    }
    __syncthreads();

    // P2: GEMM2 (32x128, K=512); wave w -> cols w*32..
    f32x4 acc2[2][2];
    #pragma unroll
    for (int m = 0; m < 2; ++m)
        #pragma unroll
        for (int n = 0; n < 2; ++n) acc2[m][n] = zf4;

    #pragma unroll 4
    for (int k = 0; k < 16; ++k) {
        bf16x8 aF[2];
        #pragma unroll
        for (int m = 0; m < 2; ++m)
            aF[m] = *(const bf16x8*)&x1L[x1_at(m * 16 + i16, k * 32 + g * 8)];
        #pragma unroll
        for (int n = 0; n < 2; ++n) {
            bf16x8 bF = *(const bf16x8*)&w2T[(size_t)(w * 32 + n * 16 + i16) * H1DIM + k * 32 + g * 8];
            #pragma unroll
            for (int m = 0; m < 2; ++m)
                acc2[m][n] = __builtin_amdgcn_mfma_f32_16x16x32_bf16(aF[m], bF, acc2[m][n], 0, 0, 0);
        }
    }
    // logits2 partials
    {
        float a2v[2], d2v[2];
        #pragma unroll
        for (int n = 0; n < 2; ++n) {
            int c = w * 32 + n * 16 + i16;
            a2v[n] = as2[c]; d2v[n] = ad2[c];
        }
        float pe[2][4], pd[2][4];
        #pragma unroll
        for (int m = 0; m < 2; ++m)
            #pragma unroll
            for (int v = 0; v < 4; ++v) {
                float e = 0.f, d = 0.f;
                #pragma unroll
                for (int n = 0; n < 2; ++n) {
                    e = fmaf(acc2[m][n][v], a2v[n], e);
                    d = fmaf(acc2[m][n][v], d2v[n], d);
                }
                pe[m][v] = e; pd[m][v] = d;
            }
        #pragma unroll
        for (int o = 1; o < 16; o <<= 1) {
            #pragma unroll
            for (int m = 0; m < 2; ++m)
                #pragma unroll
                for (int v = 0; v < 4; ++v) {
                    pe[m][v] += __shfl_xor(pe[m][v], o);
                    pd[m][v] += __shfl_xor(pd[m][v], o);
                }
        }
        if (i16 == 0) {
            #pragma unroll
            for (int m = 0; m < 2; ++m)
                #pragma unroll
                for (int v = 0; v < 4; ++v) {
                    int r = m * 16 + g * 4 + v;
                    esP[w * 32 + r] = pe[m][v];
                    edP[w * 32 + r] = pd[m][v];
                }
        }
    }
    __syncthreads();

    // P3: softmax2 (4 lanes per dest row), store unnormalized + rs2
    if (t < 128) {
        int d = t >> 2, q = t & 3;
        float edv = edP[d] + edP[32 + d] + edP[64 + d] + edP[96 + d];
        float mx = -INFINITY;
        #pragma unroll
        for (int j = 0; j < 8; ++j) {
            int s = q * 8 + j;
            if (cntB[d * NF + s]) {
                float lg = esP[s] + esP[32 + s] + esP[64 + s] + esP[96 + s] + edv;
                lg = fmaxf(lg, 0.2f * lg);
                mx = fmaxf(mx, lg);
            }
        }
        mx = fmaxf(mx, __shfl_xor(mx, 1));
        mx = fmaxf(mx, __shfl_xor(mx, 2));
        float sum = 0.f;
        #pragma unroll
        for (int j = 0; j < 8; ++j) {
            int s = q * 8 + j;
            int c = cntB[d * NF + s];
            float a = 0.f;
            if (c) {
                float lg = esP[s] + esP[32 + s] + esP[64 + s] + esP[96 + s] + edv;
                lg = fmaxf(lg, 0.2f * lg);
                a = (float)c * __expf(lg - mx);
                sum += a;
            }
            aL2[d * 33 + s] = a;
        }
        sum += __shfl_xor(sum, 1);
        sum += __shfl_xor(sum, 2);
        if (q == 0) rs2[d] = 1.0f / sum;
    }
    __syncthreads();

    // P4: column weights wn2[s] = sum_d alpha[d][s]/sum[d]
    if (t < 128) {
        int s = t >> 2, dq = t & 3;
        float p = 0.f;
        #pragma unroll
        for (int j = 0; j < 8; ++j) {
            int d = dq * 8 + j;
            p = fmaf(aL2[d * 33 + s], rs2[d], p);
        }
        p += __shfl_xor(p, 1);
        p += __shfl_xor(p, 2);
        if (dq == 0) wn2[s] = p;
    }
    __syncthreads();

    // P5: pool from register h2 + bias; gate
    {
        float wr_[2][4];
        #pragma unroll
        for (int m = 0; m < 2; ++m)
            #pragma unroll
            for (int v = 0; v < 4; ++v) wr_[m][v] = wn2[m * 16 + g * 4 + v];
        float pl[2];
        #pragma unroll
        for (int n = 0; n < 2; ++n) {
            float a = 0.f;
            #pragma unroll
            for (int m = 0; m < 2; ++m)
                #pragma unroll
                for (int v = 0; v < 4; ++v)
                    a = fmaf(wr_[m][v], acc2[m][n][v], a);
            pl[n] = a;
        }
        #pragma unroll
        for (int n = 0; n < 2; ++n) {
            pl[n] += __shfl_xor(pl[n], 16);
            pl[n] += __shfl_xor(pl[n], 32);
        }
        if (l < 16) {
            #pragma unroll
            for (int n = 0; n < 2; ++n) {
                int c = w * 32 + n * 16 + l;
                dout[(size_t)b * HID + c] = pl[n] * (1.0f / NF) + b2[c];
            }
        }
    }
    if (b == 0 && t < NF)
        dout[(size_t)NB * HID + t] = 1.0f / (1.0f + __expf(-gl[t]));
}

// ---------------------------------------------------------------------------
extern "C" void kernel_launch(void* const* d_in, const int* in_sizes, int n_in,
                              void* d_out, int out_size, void* d_ws, size_t ws_size,
                              hipStream_t stream)
{
    const float* xf    = (const float*)d_in[0];
    const float* Wa    = (const float*)d_in[1];
    const float* ba    = (const float*)d_in[2];
    const float* gamma = (const float*)d_in[3];
    const float* beta  = (const float*)d_in[4];
    const float* gl    = (const float*)d_in[5];
    const float* w1    = (const float*)d_in[6];
    const float* as1   = (const float*)d_in[7];
    const float* ad1   = (const float*)d_in[8];
    const float* b1    = (const float*)d_in[9];
    const float* w2    = (const float*)d_in[10];
    const float* as2   = (const float*)d_in[11];
    const float* ad2   = (const float*)d_in[12];
    const float* b2    = (const float*)d_in[13];
    const int*   eidx  = (const int*)d_in[14];
    const int E = in_sizes[14] / 2;
    const int* srcG = eidx;
    const int* dstG = eidx + E;
    const int epg = (E - NTOT) / NB;   // template edges per graph (graph-major)

    char* w = (char*)d_ws;
    unsigned short* w1T = (unsigned short*)w; w += (size_t)H1DIM * HID * 2;
    unsigned short* w2T = (unsigned short*)w; w += (size_t)HID * H1DIM * 2;
    unsigned short* WaT = (unsigned short*)w; w += (size_t)HID * DIN * 2;
    unsigned short* x1g = (unsigned short*)w; w += (size_t)NTOT * H1DIM * 2;  // 32 MB

    k_prep<<<(2 * HID * H1DIM + DIN * HID) / 256, 256, 0, stream>>>(
        w1, w2, Wa, w1T, w2T, WaT);

    k_gnn1<<<NB * HEADS, 128, 0, stream>>>(
        xf, WaT, ba, gamma, beta, gl, w1T, as1, ad1, b1,
        srcG, dstG, epg, x1g);

    k_gnn2<<<NB, 256, 0, stream>>>(
        x1g, w2T, as2, ad2, b2, gl, srcG, dstG, epg, (float*)d_out);
}